// Round 1
// baseline (339.233 us; speedup 1.0000x reference)
//
#include <hip/hip_runtime.h>
#include <hip/hip_bf16.h>

// Problem: x[128,64,1024] fp32; W1,W2 [1024,1024] fp32 (torch Linear, y = x @ W^T)
//   h = x @ W1^T ; spikes = LIF_scan(h) (tau=2, v_th=1, reset v=h*(1-s)) ; out = spikes @ W2^T
// Pipeline: GEMM1(fp32, VALU) -> d_out as scratch H ; scan -> spike bitmasks in ws ;
//           W2 transpose in ws ; sparse accumulate -> d_out.
// ws usage: [0, 1MB) spike masks (8192 rows x 16 u64), [1MB, 5MB) W2T. Requires ws >= 5MB.

#define TT 128
#define BB 64
#define NN 1024
#define MROWS (TT * BB)          // 8192
#define SROW  (BB * NN)          // 65536 elements per time step

// ---------------- GEMM1: C[8192,1024] = A[8192,1024] @ B[1024,1024]^T (both K-contiguous) ----
#define BM 128
#define BN 128
#define BK 16

__global__ __launch_bounds__(256) void gemm1_f32(const float* __restrict__ A,
                                                 const float* __restrict__ B,
                                                 float* __restrict__ C) {
    __shared__ float As[BK][BM];   // k-major: conflict-free float4 fragment reads
    __shared__ float Bs[BK][BN];
    const int tid = threadIdx.x;
    const int ty = tid >> 4;          // 0..15 -> C row group
    const int tx = tid & 15;          // 0..15 -> C col group
    const int rowBase = blockIdx.y * BM;
    const int colBase = blockIdx.x * BN;
    const int lr = tid >> 2;          // 0..63 staging row
    const int lk = (tid & 3) * 4;     // k offset 0/4/8/12 (64B-coalesced per 4 lanes)

    float acc[8][8] = {};

    for (int k0 = 0; k0 < NN; k0 += BK) {
#pragma unroll
        for (int h = 0; h < 2; ++h) {
            const int r = lr + h * 64;
            const float4 va = *reinterpret_cast<const float4*>(A + (size_t)(rowBase + r) * NN + k0 + lk);
            const float4 vb = *reinterpret_cast<const float4*>(B + (size_t)(colBase + r) * NN + k0 + lk);
            As[lk + 0][r] = va.x; As[lk + 1][r] = va.y; As[lk + 2][r] = va.z; As[lk + 3][r] = va.w;
            Bs[lk + 0][r] = vb.x; Bs[lk + 1][r] = vb.y; Bs[lk + 2][r] = vb.z; Bs[lk + 3][r] = vb.w;
        }
        __syncthreads();
#pragma unroll
        for (int k = 0; k < BK; ++k) {
            const float4 a0 = *reinterpret_cast<const float4*>(&As[k][ty * 8]);
            const float4 a1 = *reinterpret_cast<const float4*>(&As[k][ty * 8 + 4]);
            const float4 b0 = *reinterpret_cast<const float4*>(&Bs[k][tx * 8]);
            const float4 b1 = *reinterpret_cast<const float4*>(&Bs[k][tx * 8 + 4]);
            const float a[8] = {a0.x, a0.y, a0.z, a0.w, a1.x, a1.y, a1.z, a1.w};
            const float b[8] = {b0.x, b0.y, b0.z, b0.w, b1.x, b1.y, b1.z, b1.w};
#pragma unroll
            for (int i = 0; i < 8; ++i)
#pragma unroll
                for (int j = 0; j < 8; ++j)
                    acc[i][j] = fmaf(a[i], b[j], acc[i][j]);
        }
        __syncthreads();
    }

#pragma unroll
    for (int i = 0; i < 8; ++i) {
        float4 c0 = {acc[i][0], acc[i][1], acc[i][2], acc[i][3]};
        float4 c1 = {acc[i][4], acc[i][5], acc[i][6], acc[i][7]};
        float* p = C + (size_t)(rowBase + ty * 8 + i) * NN + colBase + tx * 8;
        *reinterpret_cast<float4*>(p)     = c0;
        *reinterpret_cast<float4*>(p + 4) = c1;
    }
}

// ---------------- LIF scan: H[t,b,n] -> spike bitmasks (one u64 per wave per t) -------------
// Exact reference arithmetic per step: h = v + (x - v)*0.5f; s = (h >= 1.f); v = s ? 0 : h.
__global__ __launch_bounds__(256) void lif_scan(const float* __restrict__ H,
                                                unsigned long long* __restrict__ mask) {
    const int g = blockIdx.x * 256 + threadIdx.x;   // 0..65535 : b*1024 + n
    const int b = g >> 10;
    const int n = g & 1023;
    const int word = n >> 6;                        // 0..15
    const bool lane0 = (threadIdx.x & 63) == 0;

    float v = 0.0f;
    float buf[4];
#pragma unroll
    for (int j = 0; j < 4; ++j) buf[j] = H[(size_t)j * SROW + g];

    for (int t0 = 0; t0 < TT; t0 += 4) {
        float nbuf[4] = {0.f, 0.f, 0.f, 0.f};
        if (t0 + 4 < TT) {
#pragma unroll
            for (int j = 0; j < 4; ++j) nbuf[j] = H[(size_t)(t0 + 4 + j) * SROW + g];
        }
#pragma unroll
        for (int j = 0; j < 4; ++j) {
            const float x = buf[j];
            const float h = v + (x - v) * 0.5f;
            const bool s = (h >= 1.0f);
            v = s ? 0.0f : h;
            const unsigned long long m = __ballot(s);
            if (lane0) mask[((size_t)(t0 + j) * BB + b) * 16 + word] = m;
        }
#pragma unroll
        for (int j = 0; j < 4; ++j) buf[j] = nbuf[j];
    }
}

// ---------------- W2 transpose: W2T[n][m] = W2[m][n] ----------------------------------------
__global__ __launch_bounds__(256) void transpose_nn(const float* __restrict__ in,
                                                    float* __restrict__ out) {
    __shared__ float tile[32][33];
    const int bx = blockIdx.x * 32, by = blockIdx.y * 32;
    {
        const int x = bx + threadIdx.x;
#pragma unroll
        for (int j = 0; j < 32; j += 8)
            tile[threadIdx.y + j][threadIdx.x] = in[(size_t)(by + threadIdx.y + j) * NN + x];
    }
    __syncthreads();
    {
        const int x = by + threadIdx.x;
#pragma unroll
        for (int j = 0; j < 32; j += 8)
            out[(size_t)(bx + threadIdx.y + j) * NN + x] = tile[threadIdx.x][threadIdx.y + j];
    }
}

// ---------------- sparse GEMM2: out[r,:] = sum_{n: spike} W2T[n,:] --------------------------
__global__ __launch_bounds__(256) void spike_matmul(const unsigned long long* __restrict__ mask,
                                                    const float* __restrict__ W2T,
                                                    float* __restrict__ out) {
    __shared__ unsigned long long sw[16];
    const int r = blockIdx.x;            // 0..8191 (= t*64 + b)
    const int tid = threadIdx.x;
    if (tid < 16) sw[tid] = mask[(size_t)r * 16 + tid];
    __syncthreads();

    float acc0 = 0.f, acc1 = 0.f, acc2 = 0.f, acc3 = 0.f;
#pragma unroll 1
    for (int w = 0; w < 16; ++w) {
        unsigned long long bits = sw[w];
        while (bits) {
            const int n = w * 64 + (__ffsll(bits) - 1);
            bits &= bits - 1;
            const float* __restrict__ row = W2T + (size_t)n * NN;
            acc0 += row[tid];
            acc1 += row[tid + 256];
            acc2 += row[tid + 512];
            acc3 += row[tid + 768];
        }
    }
    float* o = out + (size_t)r * NN;
    o[tid]       = acc0;
    o[tid + 256] = acc1;
    o[tid + 512] = acc2;
    o[tid + 768] = acc3;
}

extern "C" void kernel_launch(void* const* d_in, const int* in_sizes, int n_in,
                              void* d_out, int out_size, void* d_ws, size_t ws_size,
                              hipStream_t stream) {
    const float* x  = (const float*)d_in[0];
    const float* W1 = (const float*)d_in[1];
    const float* W2 = (const float*)d_in[2];
    float* out = (float*)d_out;

    unsigned long long* mask = (unsigned long long*)d_ws;                     // 1 MB
    float* W2T = (float*)((char*)d_ws + (size_t)MROWS * 16 * sizeof(unsigned long long)); // 4 MB

    // 1) W2^T (independent of GEMM1, issue first)
    transpose_nn<<<dim3(32, 32), dim3(32, 8), 0, stream>>>(W2, W2T);

    // 2) H = x @ W1^T  -> stored in d_out as scratch
    gemm1_f32<<<dim3(NN / BN, MROWS / BM), 256, 0, stream>>>(x, W1, out);

    // 3) LIF scan -> spike bitmasks
    lif_scan<<<SROW / 256, 256, 0, stream>>>(out, mask);

    // 4) out = spikes @ W2^T (sparse accumulate, overwrites d_out)
    spike_matmul<<<MROWS, 256, 0, stream>>>(mask, W2T, out);
}

// Round 2
// 315.295 us; speedup vs baseline: 1.0759x; 1.0759x over previous
//
#include <hip/hip_runtime.h>
#include <hip/hip_bf16.h>

// Problem: x[128,64,1024] fp32; W1,W2 [1024,1024] fp32 (torch Linear, y = x @ W^T)
//   h = x @ W1^T ; spikes = LIF_scan(h) ; out = spikes @ W2^T  (spike rate ~0.1-0.2%)
// Pipeline: GEMM1(fp32 VALU, packed-f32) -> d_out as scratch H ; scan -> spike bitmasks ;
//           W2 transpose ; sparse accumulate -> d_out.
// ws usage: [0,1MB) spike masks (8192 x 16 u64), [1MB,5MB) W2T. Requires ws >= 5MB.

#define TT 128
#define BB 64
#define NN 1024
#define MROWS (TT * BB)          // 8192
#define SROW  (BB * NN)          // 65536

typedef float v2f __attribute__((ext_vector_type(2)));

#if __has_builtin(__builtin_elementwise_fma)
#define V2FMA(a, b, c) __builtin_elementwise_fma((a), (b), (c))
#else
static __device__ __forceinline__ v2f v2fma_(v2f a, v2f b, v2f c) {
    v2f r; r[0] = fmaf(a[0], b[0], c[0]); r[1] = fmaf(a[1], b[1], c[1]); return r;
}
#define V2FMA(a, b, c) v2fma_((a), (b), (c))
#endif

// ---------------- GEMM1: C[8192,1024] = A[8192,1024] @ B[1024,1024]^T --------------------
// BM=128 x BN=64 tile, BK=16, 256 threads, 1024 blocks (4/CU -> 16 waves/CU).
// k-major LDS (padded 132/68: 16B-aligned rows, <=2-way banks), double-buffered,
// one barrier per K-step, reg-staged prefetch issued before compute.
#define BM 128
#define BN 64
#define BK 16

__global__ __launch_bounds__(256, 4) void gemm1_f32(const float* __restrict__ A,
                                                    const float* __restrict__ B,
                                                    float* __restrict__ C) {
    __shared__ float As[2][BK][132];
    __shared__ float Bs[2][BK][68];
    const int tid = threadIdx.x;
    const int ty = tid >> 4;          // 0..15 -> 8 rows each
    const int tx = tid & 15;          // 0..15 -> 4 cols each
    const int rowBase = blockIdx.y * BM;
    const int colBase = blockIdx.x * BN;
    const int sr = tid >> 2;          // 0..63 staging row
    const int sk = (tid & 3) * 4;     // k offset 0/4/8/12 (16B per lane, coalesced)

    const float* Ap0 = A + (size_t)(rowBase + sr) * NN + sk;
    const float* Ap1 = Ap0 + (size_t)64 * NN;
    const float* Bp  = B + (size_t)(colBase + sr) * NN + sk;

    v2f acc[4][4];   // [row-pair][col] ; lanes = rows (2rp, 2rp+1)
#pragma unroll
    for (int i = 0; i < 4; ++i)
#pragma unroll
        for (int j = 0; j < 4; ++j) acc[i][j] = (v2f){0.f, 0.f};

    float4 ra0 = *(const float4*)Ap0;
    float4 ra1 = *(const float4*)Ap1;
    float4 rb  = *(const float4*)Bp;

#define STW(buf)                                                                       \
    do {                                                                               \
        As[buf][sk + 0][sr] = ra0.x; As[buf][sk + 1][sr] = ra0.y;                      \
        As[buf][sk + 2][sr] = ra0.z; As[buf][sk + 3][sr] = ra0.w;                      \
        As[buf][sk + 0][sr + 64] = ra1.x; As[buf][sk + 1][sr + 64] = ra1.y;            \
        As[buf][sk + 2][sr + 64] = ra1.z; As[buf][sk + 3][sr + 64] = ra1.w;            \
        Bs[buf][sk + 0][sr] = rb.x;  Bs[buf][sk + 1][sr] = rb.y;                       \
        Bs[buf][sk + 2][sr] = rb.z;  Bs[buf][sk + 3][sr] = rb.w;                       \
    } while (0)

    STW(0);
    __syncthreads();

    const int NT = NN / BK;           // 64
    for (int t = 0; t < NT; ++t) {
        const int cur = t & 1;
        if (t < NT - 1) {             // issue next-tile loads early (latency under compute)
            const int ko = (t + 1) * BK;
            ra0 = *(const float4*)(Ap0 + ko);
            ra1 = *(const float4*)(Ap1 + ko);
            rb  = *(const float4*)(Bp + ko);
        }
#pragma unroll
        for (int k = 0; k < BK; ++k) {
            const v2f* ap = (const v2f*)&As[cur][k][ty * 8];      // 4 row-pairs (b128-able)
            const float4 bf = *(const float4*)&Bs[cur][k][tx * 4];
            const float bb[4] = {bf.x, bf.y, bf.z, bf.w};
            const v2f a0 = ap[0], a1 = ap[1], a2 = ap[2], a3 = ap[3];
#pragma unroll
            for (int j = 0; j < 4; ++j) {
                const v2f bd = {bb[j], bb[j]};
                acc[0][j] = V2FMA(a0, bd, acc[0][j]);
                acc[1][j] = V2FMA(a1, bd, acc[1][j]);
                acc[2][j] = V2FMA(a2, bd, acc[2][j]);
                acc[3][j] = V2FMA(a3, bd, acc[3][j]);
            }
        }
        if (t < NT - 1) STW(cur ^ 1);
        __syncthreads();
    }
#undef STW

    float* Cp = C + (size_t)(rowBase + ty * 8) * NN + colBase + tx * 4;
#pragma unroll
    for (int rp = 0; rp < 4; ++rp) {
        float4 lo = {acc[rp][0][0], acc[rp][1][0], acc[rp][2][0], acc[rp][3][0]};
        float4 hi = {acc[rp][0][1], acc[rp][1][1], acc[rp][2][1], acc[rp][3][1]};
        *(float4*)(Cp + (size_t)(2 * rp) * NN)     = lo;
        *(float4*)(Cp + (size_t)(2 * rp + 1) * NN) = hi;
    }
}

// ---------------- LIF scan: H[t,b,n] -> spike bitmasks --------------------------------------
// Exact reference arithmetic: h = v + (x - v)*0.5f; s = (h >= 1.f); v = s ? 0 : h.
// 8-deep prefetch: ~8KB in flight per CU (Little's law target ~9KB at 6.3 TB/s, 375ns).
__global__ __launch_bounds__(256) void lif_scan(const float* __restrict__ H,
                                                unsigned long long* __restrict__ mask) {
    const int g = blockIdx.x * 256 + threadIdx.x;   // b*1024 + n
    const int b = g >> 10;
    const int n = g & 1023;
    const int word = n >> 6;
    const bool lane0 = (threadIdx.x & 63) == 0;

    float v = 0.0f;
    float buf[8];
#pragma unroll
    for (int j = 0; j < 8; ++j) buf[j] = H[(size_t)j * SROW + g];

    for (int t0 = 0; t0 < TT; t0 += 8) {
        float nbuf[8];
        if (t0 + 8 < TT) {
#pragma unroll
            for (int j = 0; j < 8; ++j) nbuf[j] = H[(size_t)(t0 + 8 + j) * SROW + g];
        } else {
#pragma unroll
            for (int j = 0; j < 8; ++j) nbuf[j] = 0.f;
        }
#pragma unroll
        for (int j = 0; j < 8; ++j) {
            const float x = buf[j];
            const float h = v + (x - v) * 0.5f;
            const bool s = (h >= 1.0f);
            v = s ? 0.0f : h;
            const unsigned long long m = __ballot(s);
            if (lane0) mask[((size_t)(t0 + j) * BB + b) * 16 + word] = m;
        }
#pragma unroll
        for (int j = 0; j < 8; ++j) buf[j] = nbuf[j];
    }
}

// ---------------- W2 transpose ---------------------------------------------------------------
__global__ __launch_bounds__(256) void transpose_nn(const float* __restrict__ in,
                                                    float* __restrict__ out) {
    __shared__ float tile[32][33];
    const int bx = blockIdx.x * 32, by = blockIdx.y * 32;
    {
        const int x = bx + threadIdx.x;
#pragma unroll
        for (int j = 0; j < 32; j += 8)
            tile[threadIdx.y + j][threadIdx.x] = in[(size_t)(by + threadIdx.y + j) * NN + x];
    }
    __syncthreads();
    {
        const int x = by + threadIdx.x;
#pragma unroll
        for (int j = 0; j < 32; j += 8)
            out[(size_t)(bx + threadIdx.y + j) * NN + x] = tile[threadIdx.x][threadIdx.y + j];
    }
}

// ---------------- sparse GEMM2: out[r,:] = sum_{n: spike} W2T[n,:] ---------------------------
__global__ __launch_bounds__(256) void spike_matmul(const unsigned long long* __restrict__ mask,
                                                    const float* __restrict__ W2T,
                                                    float* __restrict__ out) {
    __shared__ unsigned long long sw[16];
    const int r = blockIdx.x;
    const int tid = threadIdx.x;
    if (tid < 16) sw[tid] = mask[(size_t)r * 16 + tid];
    __syncthreads();

    float acc0 = 0.f, acc1 = 0.f, acc2 = 0.f, acc3 = 0.f;
#pragma unroll 1
    for (int w = 0; w < 16; ++w) {
        unsigned long long bits = sw[w];
        while (bits) {
            const int n = w * 64 + (__ffsll(bits) - 1);
            bits &= bits - 1;
            const float* __restrict__ row = W2T + (size_t)n * NN;
            acc0 += row[tid];
            acc1 += row[tid + 256];
            acc2 += row[tid + 512];
            acc3 += row[tid + 768];
        }
    }
    float* o = out + (size_t)r * NN;
    o[tid]       = acc0;
    o[tid + 256] = acc1;
    o[tid + 512] = acc2;
    o[tid + 768] = acc3;
}

extern "C" void kernel_launch(void* const* d_in, const int* in_sizes, int n_in,
                              void* d_out, int out_size, void* d_ws, size_t ws_size,
                              hipStream_t stream) {
    const float* x  = (const float*)d_in[0];
    const float* W1 = (const float*)d_in[1];
    const float* W2 = (const float*)d_in[2];
    float* out = (float*)d_out;

    unsigned long long* mask = (unsigned long long*)d_ws;                                  // 1 MB
    float* W2T = (float*)((char*)d_ws + (size_t)MROWS * 16 * sizeof(unsigned long long)); // 4 MB

    transpose_nn<<<dim3(32, 32), dim3(32, 8), 0, stream>>>(W2, W2T);
    gemm1_f32<<<dim3(NN / BN, MROWS / BM), 256, 0, stream>>>(x, W1, out);
    lif_scan<<<SROW / 256, 256, 0, stream>>>(out, mask);
    spike_matmul<<<MROWS, 256, 0, stream>>>(mask, W2T, out);
}

// Round 3
// 192.031 us; speedup vs baseline: 1.7666x; 1.6419x over previous
//
#include <hip/hip_runtime.h>
#include <hip/hip_bf16.h>
#include <stdint.h>

// Problem: x[128,64,1024] fp32; W1,W2 [1024,1024] fp32 (torch Linear, y = x @ W^T)
//   h = x @ W1^T ; spikes = LIF_scan(h) ; out = spikes @ W2^T  (spike rate ~0.1-0.2%)
//
// GEMM1 via f16 2-split on MFMA: a = a0 + a1/4096 (+ r ~ 2^-22|a|),
//   A.B^T ~= A0B0 + (A0B1s + A1sB0)/4096   (3 products, m97-style 128^2 MFMA GEMM)
// ws layout (primary path, needs 43 MiB):
//   [0,1M) spike masks | [1M,5M) W2T | [5M) A0 16.78M | [22M) A1s | [39M) B0 2M | [41M) B1s
// Fallback (ws < 43 MiB): round-2 fp32 VALU pipeline (ws 5 MiB).

#define TT 128
#define BB 64
#define NN 1024
#define MROWS (TT * BB)          // 8192
#define SROW  (BB * NN)          // 65536
#define MiB   ((size_t)1048576)

typedef _Float16 h8  __attribute__((ext_vector_type(8)));
typedef _Float16 h4v __attribute__((ext_vector_type(4)));
typedef float    f4  __attribute__((ext_vector_type(4)));
typedef float v2f __attribute__((ext_vector_type(2)));

#if __has_builtin(__builtin_elementwise_fma)
#define V2FMA(a, b, c) __builtin_elementwise_fma((a), (b), (c))
#else
static __device__ __forceinline__ v2f v2fma_(v2f a, v2f b, v2f c) {
    v2f r; r[0] = fmaf(a[0], b[0], c[0]); r[1] = fmaf(a[1], b[1], c[1]); return r;
}
#define V2FMA(a, b, c) v2fma_((a), (b), (c))
#endif

#define GL2LDS(g, l) __builtin_amdgcn_global_load_lds(                         \
    (const __attribute__((address_space(1))) void*)(const void*)(g),           \
    (__attribute__((address_space(3))) void*)(void*)(l), 16, 0, 0)

// ---------------- split: fp32 -> (f16 hi, f16 lo*4096) -------------------------------------
__global__ __launch_bounds__(256) void split2_f16(const float* __restrict__ src,
                                                  _Float16* __restrict__ d0,
                                                  _Float16* __restrict__ d1, int n4) {
    const int i = blockIdx.x * 256 + threadIdx.x;
    if (i >= n4) return;
    const float4 v = reinterpret_cast<const float4*>(src)[i];
    const float f[4] = {v.x, v.y, v.z, v.w};
    h4v a0, a1;
#pragma unroll
    for (int j = 0; j < 4; ++j) {
        const _Float16 c = (_Float16)f[j];
        a0[j] = c;
        a1[j] = (_Float16)((f[j] - (float)c) * 4096.0f);  // scaled: no f16 subnormals
    }
    reinterpret_cast<h4v*>(d0)[i] = a0;
    reinterpret_cast<h4v*>(d1)[i] = a1;
}

// ---------------- MFMA GEMM: C[8192,1024] f32 = sum of 3 f16 products ----------------------
// m97 structure: 128x128 tile, 4 waves (2x2), 16x16x32 f16 MFMA, 4x4 frags/wave,
// K_STEP=32, single-buffered LDS, global_load_lds width-16 staging, 2 barriers/K-step.
__global__ __launch_bounds__(256, 2) void gemm_split(const _Float16* __restrict__ A0,
                                                     const _Float16* __restrict__ A1,
                                                     const _Float16* __restrict__ B0,
                                                     const _Float16* __restrict__ B1,
                                                     float* __restrict__ C) {
    __shared__ _Float16 As[128 * 32];
    __shared__ _Float16 Bs[128 * 32];
    const int tid  = threadIdx.x;
    const int lane = tid & 63;
    const int wid  = tid >> 6;
    const int wr   = wid >> 1, wc = wid & 1;
    const int rowBase = blockIdx.y * 128;
    const int colBase = blockIdx.x * 128;

    // staging: wave w, inst i covers LDS rows [w*32+i*16, +16); lane covers row l>>2, 16B chunk l&3
    const size_t aOff0 = (size_t)(rowBase + wid * 32 + (lane >> 2)) * NN + (lane & 3) * 8;
    const size_t aOff1 = aOff0 + (size_t)16 * NN;
    const size_t bOff0 = (size_t)(colBase + wid * 32 + (lane >> 2)) * NN + (lane & 3) * 8;
    const size_t bOff1 = bOff0 + (size_t)16 * NN;
    const int ldsW0 = (wid * 2 + 0) * 512;   // halves (1024 B per wave-inst)
    const int ldsW1 = (wid * 2 + 1) * 512;

    // fragment read offsets (halves): row stride 32, k-offset (lane>>4)*8
    const int fA = (wr * 64 + (lane & 15)) * 32 + (lane >> 4) * 8;
    const int fB = (wc * 64 + (lane & 15)) * 32 + (lane >> 4) * 8;

    f4 acc0[4][4], acc1[4][4];
#pragma unroll
    for (int i = 0; i < 4; ++i)
#pragma unroll
        for (int j = 0; j < 4; ++j) { acc0[i][j] = (f4)0.0f; acc1[i][j] = (f4)0.0f; }

#define STAGE(AG, BG, K0)                                 \
    do {                                                  \
        GL2LDS((AG) + aOff0 + (K0), &As[ldsW0]);          \
        GL2LDS((AG) + aOff1 + (K0), &As[ldsW1]);          \
        GL2LDS((BG) + bOff0 + (K0), &Bs[ldsW0]);          \
        GL2LDS((BG) + bOff1 + (K0), &Bs[ldsW1]);          \
    } while (0)

#define PASS(AG, BG, ACC)                                                          \
    for (int k0 = 0; k0 < NN; k0 += 32) {                                          \
        STAGE(AG, BG, k0);                                                         \
        __syncthreads();                                                           \
        {                                                                          \
            h8 af0 = *(const h8*)&As[fA];                                          \
            h8 af1 = *(const h8*)&As[fA + 512];                                    \
            h8 af2 = *(const h8*)&As[fA + 1024];                                   \
            h8 af3 = *(const h8*)&As[fA + 1536];                                   \
            h8 bf0 = *(const h8*)&Bs[fB];                                          \
            h8 bf1 = *(const h8*)&Bs[fB + 512];                                    \
            h8 bf2 = *(const h8*)&Bs[fB + 1024];                                   \
            h8 bf3 = *(const h8*)&Bs[fB + 1536];                                   \
            ACC[0][0] = __builtin_amdgcn_mfma_f32_16x16x32_f16(af0, bf0, ACC[0][0], 0, 0, 0); \
            ACC[0][1] = __builtin_amdgcn_mfma_f32_16x16x32_f16(af0, bf1, ACC[0][1], 0, 0, 0); \
            ACC[0][2] = __builtin_amdgcn_mfma_f32_16x16x32_f16(af0, bf2, ACC[0][2], 0, 0, 0); \
            ACC[0][3] = __builtin_amdgcn_mfma_f32_16x16x32_f16(af0, bf3, ACC[0][3], 0, 0, 0); \
            ACC[1][0] = __builtin_amdgcn_mfma_f32_16x16x32_f16(af1, bf0, ACC[1][0], 0, 0, 0); \
            ACC[1][1] = __builtin_amdgcn_mfma_f32_16x16x32_f16(af1, bf1, ACC[1][1], 0, 0, 0); \
            ACC[1][2] = __builtin_amdgcn_mfma_f32_16x16x32_f16(af1, bf2, ACC[1][2], 0, 0, 0); \
            ACC[1][3] = __builtin_amdgcn_mfma_f32_16x16x32_f16(af1, bf3, ACC[1][3], 0, 0, 0); \
            ACC[2][0] = __builtin_amdgcn_mfma_f32_16x16x32_f16(af2, bf0, ACC[2][0], 0, 0, 0); \
            ACC[2][1] = __builtin_amdgcn_mfma_f32_16x16x32_f16(af2, bf1, ACC[2][1], 0, 0, 0); \
            ACC[2][2] = __builtin_amdgcn_mfma_f32_16x16x32_f16(af2, bf2, ACC[2][2], 0, 0, 0); \
            ACC[2][3] = __builtin_amdgcn_mfma_f32_16x16x32_f16(af2, bf3, ACC[2][3], 0, 0, 0); \
            ACC[3][0] = __builtin_amdgcn_mfma_f32_16x16x32_f16(af3, bf0, ACC[3][0], 0, 0, 0); \
            ACC[3][1] = __builtin_amdgcn_mfma_f32_16x16x32_f16(af3, bf1, ACC[3][1], 0, 0, 0); \
            ACC[3][2] = __builtin_amdgcn_mfma_f32_16x16x32_f16(af3, bf2, ACC[3][2], 0, 0, 0); \
            ACC[3][3] = __builtin_amdgcn_mfma_f32_16x16x32_f16(af3, bf3, ACC[3][3], 0, 0, 0); \
        }                                                                          \
        __syncthreads();                                                           \
    }

    PASS(A0, B0, acc0)          // main product
    PASS(A0, B1, acc1)          // cross products, both scaled 2^-12
    PASS(A1, B0, acc1)
#undef PASS
#undef STAGE

    // C/D layout (m89-verified): col = lane&15, row = (lane>>4)*4 + reg
    const int orow = rowBase + wr * 64 + (lane >> 4) * 4;
    const int ocol = colBase + wc * 64 + (lane & 15);
#pragma unroll
    for (int i = 0; i < 4; ++i)
#pragma unroll
        for (int j = 0; j < 4; ++j)
#pragma unroll
            for (int q = 0; q < 4; ++q)
                C[(size_t)(orow + i * 16 + q) * NN + ocol + j * 16] =
                    acc0[i][j][q] + acc1[i][j][q] * (1.0f / 4096.0f);
}

// ---------------- LIF scan: H[t,b,n] -> spike bitmasks (exact reference arithmetic) ---------
__global__ __launch_bounds__(256) void lif_scan(const float* __restrict__ H,
                                                unsigned long long* __restrict__ mask) {
    const int g = blockIdx.x * 256 + threadIdx.x;
    const int b = g >> 10;
    const int n = g & 1023;
    const int word = n >> 6;
    const bool lane0 = (threadIdx.x & 63) == 0;

    float v = 0.0f;
    float buf[8];
#pragma unroll
    for (int j = 0; j < 8; ++j) buf[j] = H[(size_t)j * SROW + g];

    for (int t0 = 0; t0 < TT; t0 += 8) {
        float nbuf[8];
        if (t0 + 8 < TT) {
#pragma unroll
            for (int j = 0; j < 8; ++j) nbuf[j] = H[(size_t)(t0 + 8 + j) * SROW + g];
        } else {
#pragma unroll
            for (int j = 0; j < 8; ++j) nbuf[j] = 0.f;
        }
#pragma unroll
        for (int j = 0; j < 8; ++j) {
            const float x = buf[j];
            const float h = v + (x - v) * 0.5f;
            const bool s = (h >= 1.0f);
            v = s ? 0.0f : h;
            const unsigned long long m = __ballot(s);
            if (lane0) mask[((size_t)(t0 + j) * BB + b) * 16 + word] = m;
        }
#pragma unroll
        for (int j = 0; j < 8; ++j) buf[j] = nbuf[j];
    }
}

// ---------------- W2 transpose --------------------------------------------------------------
__global__ __launch_bounds__(256) void transpose_nn(const float* __restrict__ in,
                                                    float* __restrict__ out) {
    __shared__ float tile[32][33];
    const int bx = blockIdx.x * 32, by = blockIdx.y * 32;
    {
        const int x = bx + threadIdx.x;
#pragma unroll
        for (int j = 0; j < 32; j += 8)
            tile[threadIdx.y + j][threadIdx.x] = in[(size_t)(by + threadIdx.y + j) * NN + x];
    }
    __syncthreads();
    {
        const int x = by + threadIdx.x;
#pragma unroll
        for (int j = 0; j < 32; j += 8)
            out[(size_t)(bx + threadIdx.y + j) * NN + x] = tile[threadIdx.x][threadIdx.y + j];
    }
}

// ---------------- sparse GEMM2: out[r,:] = sum_{n: spike} W2T[n,:] ---------------------------
__global__ __launch_bounds__(256) void spike_matmul(const unsigned long long* __restrict__ mask,
                                                    const float* __restrict__ W2T,
                                                    float* __restrict__ out) {
    __shared__ unsigned long long sw[16];
    const int r = blockIdx.x;
    const int tid = threadIdx.x;
    if (tid < 16) sw[tid] = mask[(size_t)r * 16 + tid];
    __syncthreads();

    float acc0 = 0.f, acc1 = 0.f, acc2 = 0.f, acc3 = 0.f;
#pragma unroll 1
    for (int w = 0; w < 16; ++w) {
        unsigned long long bits = sw[w];
        while (bits) {
            const int n = w * 64 + (__ffsll(bits) - 1);
            bits &= bits - 1;
            const float* __restrict__ row = W2T + (size_t)n * NN;
            acc0 += row[tid];
            acc1 += row[tid + 256];
            acc2 += row[tid + 512];
            acc3 += row[tid + 768];
        }
    }
    float* o = out + (size_t)r * NN;
    o[tid]       = acc0;
    o[tid + 256] = acc1;
    o[tid + 512] = acc2;
    o[tid + 768] = acc3;
}

// ---------------- fallback fp32 GEMM (round-2, used only if ws too small) --------------------
#define BM 128
#define BN 64
#define BK 16
__global__ __launch_bounds__(256, 4) void gemm1_f32(const float* __restrict__ A,
                                                    const float* __restrict__ B,
                                                    float* __restrict__ C) {
    __shared__ float Asb[2][BK][132];
    __shared__ float Bsb[2][BK][68];
    const int tid = threadIdx.x;
    const int ty = tid >> 4;
    const int tx = tid & 15;
    const int rowBase = blockIdx.y * BM;
    const int colBase = blockIdx.x * BN;
    const int sr = tid >> 2;
    const int sk = (tid & 3) * 4;

    const float* Ap0 = A + (size_t)(rowBase + sr) * NN + sk;
    const float* Ap1 = Ap0 + (size_t)64 * NN;
    const float* Bp  = B + (size_t)(colBase + sr) * NN + sk;

    v2f acc[4][4];
#pragma unroll
    for (int i = 0; i < 4; ++i)
#pragma unroll
        for (int j = 0; j < 4; ++j) acc[i][j] = (v2f){0.f, 0.f};

    float4 ra0 = *(const float4*)Ap0;
    float4 ra1 = *(const float4*)Ap1;
    float4 rb  = *(const float4*)Bp;

#define STW(buf)                                                                       \
    do {                                                                               \
        Asb[buf][sk + 0][sr] = ra0.x; Asb[buf][sk + 1][sr] = ra0.y;                    \
        Asb[buf][sk + 2][sr] = ra0.z; Asb[buf][sk + 3][sr] = ra0.w;                    \
        Asb[buf][sk + 0][sr + 64] = ra1.x; Asb[buf][sk + 1][sr + 64] = ra1.y;          \
        Asb[buf][sk + 2][sr + 64] = ra1.z; Asb[buf][sk + 3][sr + 64] = ra1.w;          \
        Bsb[buf][sk + 0][sr] = rb.x;  Bsb[buf][sk + 1][sr] = rb.y;                     \
        Bsb[buf][sk + 2][sr] = rb.z;  Bsb[buf][sk + 3][sr] = rb.w;                     \
    } while (0)

    STW(0);
    __syncthreads();
    const int NT = NN / BK;
    for (int t = 0; t < NT; ++t) {
        const int cur = t & 1;
        if (t < NT - 1) {
            const int ko = (t + 1) * BK;
            ra0 = *(const float4*)(Ap0 + ko);
            ra1 = *(const float4*)(Ap1 + ko);
            rb  = *(const float4*)(Bp + ko);
        }
#pragma unroll
        for (int k = 0; k < BK; ++k) {
            const v2f* ap = (const v2f*)&Asb[cur][k][ty * 8];
            const float4 bf = *(const float4*)&Bsb[cur][k][tx * 4];
            const float bb[4] = {bf.x, bf.y, bf.z, bf.w};
            const v2f a0 = ap[0], a1 = ap[1], a2 = ap[2], a3 = ap[3];
#pragma unroll
            for (int j = 0; j < 4; ++j) {
                const v2f bd = {bb[j], bb[j]};
                acc[0][j] = V2FMA(a0, bd, acc[0][j]);
                acc[1][j] = V2FMA(a1, bd, acc[1][j]);
                acc[2][j] = V2FMA(a2, bd, acc[2][j]);
                acc[3][j] = V2FMA(a3, bd, acc[3][j]);
            }
        }
        if (t < NT - 1) STW(cur ^ 1);
        __syncthreads();
    }
#undef STW
    float* Cp = C + (size_t)(rowBase + ty * 8) * NN + colBase + tx * 4;
#pragma unroll
    for (int rp = 0; rp < 4; ++rp) {
        float4 lo = {acc[rp][0][0], acc[rp][1][0], acc[rp][2][0], acc[rp][3][0]};
        float4 hi = {acc[rp][0][1], acc[rp][1][1], acc[rp][2][1], acc[rp][3][1]};
        *(float4*)(Cp + (size_t)(2 * rp) * NN)     = lo;
        *(float4*)(Cp + (size_t)(2 * rp + 1) * NN) = hi;
    }
}

extern "C" void kernel_launch(void* const* d_in, const int* in_sizes, int n_in,
                              void* d_out, int out_size, void* d_ws, size_t ws_size,
                              hipStream_t stream) {
    const float* x  = (const float*)d_in[0];
    const float* W1 = (const float*)d_in[1];
    const float* W2 = (const float*)d_in[2];
    float* out = (float*)d_out;

    unsigned long long* mask = (unsigned long long*)d_ws;
    float* W2T = (float*)((char*)d_ws + 1 * MiB);

    if (ws_size >= 43 * MiB) {
        _Float16* A0 = (_Float16*)((char*)d_ws + 5 * MiB);
        _Float16* A1 = (_Float16*)((char*)d_ws + 22 * MiB);
        _Float16* B0 = (_Float16*)((char*)d_ws + 39 * MiB);
        _Float16* B1 = (_Float16*)((char*)d_ws + 41 * MiB);

        split2_f16<<<8192, 256, 0, stream>>>(x, A0, A1, MROWS * NN / 4);
        split2_f16<<<1024, 256, 0, stream>>>(W1, B0, B1, NN * NN / 4);
        transpose_nn<<<dim3(32, 32), dim3(32, 8), 0, stream>>>(W2, W2T);
        gemm_split<<<dim3(NN / 128, MROWS / 128), 256, 0, stream>>>(A0, A1, B0, B1, out);
    } else {
        transpose_nn<<<dim3(32, 32), dim3(32, 8), 0, stream>>>(W2, W2T);
        gemm1_f32<<<dim3(NN / BN, MROWS / BM), 256, 0, stream>>>(x, W1, out);
    }
    lif_scan<<<SROW / 256, 256, 0, stream>>>(out, mask);
    spike_matmul<<<MROWS, 256, 0, stream>>>(mask, W2T, out);
}

// Round 5
// 181.251 us; speedup vs baseline: 1.8716x; 1.0595x over previous
//
#include <hip/hip_runtime.h>
#include <hip/hip_bf16.h>
#include <stdint.h>

// Problem: x[128,64,1024] fp32; W1,W2 [1024,1024] fp32 (torch Linear, y = x @ W^T)
//   h = x @ W1^T ; spikes = LIF_scan(h) ; out = spikes @ W2^T  (spike rate ~0.1-0.2%)
//
// GEMM1 via f16 2-split on MFMA: a = a0 + a1/4096 (+ r ~ 2^-22|a|),
//   A.B^T ~= A0B0 + (A0B1s + A1sB0)/4096
// Round 4 (resubmit; round-4 bench never ran — broker timeout): single merged K-loop
// (stage A0,A1,B0,B1 once, 48 MFMA/phase), double-buffered LDS with one barrier/phase,
// both-sides chunk swizzle (rule #21) for 2-way (free) LDS reads.
// ws (needs 43 MiB): [0,1M) masks | [1,5M) W2T | [5M) A0 | [22M) A1 | [39M) B0 | [41M) B1
// Fallback (ws < 43 MiB): fp32 VALU pipeline.

#define TT 128
#define BB 64
#define NN 1024
#define MROWS (TT * BB)          // 8192
#define SROW  (BB * NN)          // 65536
#define MiB   ((size_t)1048576)

typedef _Float16 h8  __attribute__((ext_vector_type(8)));
typedef _Float16 h4v __attribute__((ext_vector_type(4)));
typedef float    f4  __attribute__((ext_vector_type(4)));
typedef float    v2f __attribute__((ext_vector_type(2)));

#if __has_builtin(__builtin_elementwise_fma)
#define V2FMA(a, b, c) __builtin_elementwise_fma((a), (b), (c))
#else
static __device__ __forceinline__ v2f v2fma_(v2f a, v2f b, v2f c) {
    v2f r; r[0] = fmaf(a[0], b[0], c[0]); r[1] = fmaf(a[1], b[1], c[1]); return r;
}
#define V2FMA(a, b, c) v2fma_((a), (b), (c))
#endif

#define GL2LDS(g, l) __builtin_amdgcn_global_load_lds(                         \
    (const __attribute__((address_space(1))) void*)(const void*)(g),           \
    (__attribute__((address_space(3))) void*)(void*)(l), 16, 0, 0)

// ---------------- prep: split x, split W1, transpose W2 — one fused grid ---------------------
__global__ __launch_bounds__(256) void prep(const float* __restrict__ x,
                                            const float* __restrict__ W1,
                                            const float* __restrict__ W2,
                                            _Float16* __restrict__ A0, _Float16* __restrict__ A1,
                                            _Float16* __restrict__ B0, _Float16* __restrict__ B1,
                                            float* __restrict__ W2T) {
    const int nb = blockIdx.x;
    const int tid = threadIdx.x;
    if (nb < 8192 + 1024) {
        const bool isX = nb < 8192;
        const float* src = isX ? x : W1;
        _Float16* d0 = isX ? A0 : B0;
        _Float16* d1 = isX ? A1 : B1;
        const int i = (isX ? nb : nb - 8192) * 256 + tid;
        const float4 v = reinterpret_cast<const float4*>(src)[i];
        const float f[4] = {v.x, v.y, v.z, v.w};
        h4v a0, a1;
#pragma unroll
        for (int j = 0; j < 4; ++j) {
            const _Float16 c = (_Float16)f[j];
            a0[j] = c;
            a1[j] = (_Float16)((f[j] - (float)c) * 4096.0f);  // scaled: no f16 subnormals
        }
        reinterpret_cast<h4v*>(d0)[i] = a0;
        reinterpret_cast<h4v*>(d1)[i] = a1;
    } else {
        __shared__ float tile[32][33];
        const int tIdx = nb - 9216;
        const int bx = (tIdx & 31) * 32, by = (tIdx >> 5) * 32;
        const int tx = tid & 31, ty = tid >> 5;          // 32 x 8
#pragma unroll
        for (int j = 0; j < 32; j += 8)
            tile[ty + j][tx] = W2[(size_t)(by + ty + j) * NN + bx + tx];
        __syncthreads();
#pragma unroll
        for (int j = 0; j < 32; j += 8)
            W2T[(size_t)(bx + ty + j) * NN + by + tx] = tile[tx][ty + j];
    }
}

// ---------------- MFMA GEMM: C[8192,1024] f32, merged 3-product K-loop ----------------------
// 128x128 tile, 4 waves (2x2), 16x16x32 f16 MFMA, 4x4 frags/wave/product.
// LDS tile layout (per array, per buffer): [row 0..127][k 0..31] f16, row = 64B = 4 chunks
// of 16B; physical chunk slot s holds logical chunk s ^ ((row>>1)&3)  (both-sides swizzle:
// applied to global source of global_load_lds AND to fragment-read addresses).
__global__ __launch_bounds__(256, 2) void gemm_split(const _Float16* __restrict__ A0,
                                                     const _Float16* __restrict__ A1,
                                                     const _Float16* __restrict__ B0,
                                                     const _Float16* __restrict__ B1,
                                                     float* __restrict__ C) {
    __shared__ _Float16 As0[2][4096], As1[2][4096], Bs0[2][4096], Bs1[2][4096];
    const int tid  = threadIdx.x;
    const int lane = tid & 63;
    const int wid  = tid >> 6;
    const int wr   = wid >> 1, wc = wid & 1;
    const int rowBase = blockIdx.y * 128;
    const int colBase = blockIdx.x * 128;

    // staging: wave w covers LDS rows [w*32, w*32+32) as two 1KB insts (16 rows each).
    // lane l -> row r0 + (l>>2), slot l&3; global chunk = (l&3) ^ ((row>>1)&3).
    const int srow = wid * 32 + (lane >> 2);                 // h=0 row; h=1 adds 16 (same swz:
    const int swz  = (((lane & 3) ^ ((srow >> 1) & 3)) << 3); // rows r,r+16 share (r>>1)&3? bit4 only -> yes)
    const size_t aOff0 = (size_t)(rowBase + srow) * NN + swz;
    const size_t aOff1 = aOff0 + (size_t)16 * NN;
    const size_t bOff0 = (size_t)(colBase + srow) * NN + swz;
    const size_t bOff1 = bOff0 + (size_t)16 * NN;
    const int ldsB0 = wid * 1024;                            // f16 elems
    const int ldsB1 = wid * 1024 + 512;

    // fragment read addrs: row in tile, logical chunk = lane>>4, phys = logical ^ ((row>>1)&3)
    int fA[4], fB[4];
#pragma unroll
    for (int i = 0; i < 4; ++i) {
        const int ra = wr * 64 + i * 16 + (lane & 15);
        const int rb = wc * 64 + i * 16 + (lane & 15);
        fA[i] = ra * 32 + (((lane >> 4) ^ ((ra >> 1) & 3)) << 3);
        fB[i] = rb * 32 + (((lane >> 4) ^ ((rb >> 1) & 3)) << 3);
    }

    f4 acc0[4][4], acc1[4][4];
#pragma unroll
    for (int i = 0; i < 4; ++i)
#pragma unroll
        for (int j = 0; j < 4; ++j) { acc0[i][j] = (f4)0.0f; acc1[i][j] = (f4)0.0f; }

#define STAGE(bi, K0)                                     \
    do {                                                  \
        GL2LDS(A0 + aOff0 + (K0), &As0[bi][ldsB0]);       \
        GL2LDS(A0 + aOff1 + (K0), &As0[bi][ldsB1]);       \
        GL2LDS(A1 + aOff0 + (K0), &As1[bi][ldsB0]);       \
        GL2LDS(A1 + aOff1 + (K0), &As1[bi][ldsB1]);       \
        GL2LDS(B0 + bOff0 + (K0), &Bs0[bi][ldsB0]);       \
        GL2LDS(B0 + bOff1 + (K0), &Bs0[bi][ldsB1]);       \
        GL2LDS(B1 + bOff0 + (K0), &Bs1[bi][ldsB0]);       \
        GL2LDS(B1 + bOff1 + (K0), &Bs1[bi][ldsB1]);       \
    } while (0)

    STAGE(0, 0);
    __syncthreads();

    const int NT = NN / 32;                  // 32 phases
    for (int t = 0; t < NT; ++t) {
        const int cur = t & 1;
        if (t < NT - 1) STAGE(cur ^ 1, (t + 1) * 32);   // issue next-tile loads before MFMA
        h8 a0f[4], a1f[4], b0f[4], b1f[4];
#pragma unroll
        for (int i = 0; i < 4; ++i) {
            a0f[i] = *(const h8*)&As0[cur][fA[i]];
            a1f[i] = *(const h8*)&As1[cur][fA[i]];
            b0f[i] = *(const h8*)&Bs0[cur][fB[i]];
            b1f[i] = *(const h8*)&Bs1[cur][fB[i]];
        }
#pragma unroll
        for (int i = 0; i < 4; ++i)
#pragma unroll
            for (int j = 0; j < 4; ++j) {
                acc0[i][j] = __builtin_amdgcn_mfma_f32_16x16x32_f16(a0f[i], b0f[j], acc0[i][j], 0, 0, 0);
                acc1[i][j] = __builtin_amdgcn_mfma_f32_16x16x32_f16(a0f[i], b1f[j], acc1[i][j], 0, 0, 0);
                acc1[i][j] = __builtin_amdgcn_mfma_f32_16x16x32_f16(a1f[i], b0f[j], acc1[i][j], 0, 0, 0);
            }
        __syncthreads();    // drains stage vmcnt + protects buffer reuse
    }
#undef STAGE

    // C/D layout (m89-verified): col = lane&15, row = (lane>>4)*4 + reg
    const int orow = rowBase + wr * 64 + (lane >> 4) * 4;
    const int ocol = colBase + wc * 64 + (lane & 15);
#pragma unroll
    for (int i = 0; i < 4; ++i)
#pragma unroll
        for (int j = 0; j < 4; ++j)
#pragma unroll
            for (int q = 0; q < 4; ++q)
                C[(size_t)(orow + i * 16 + q) * NN + ocol + j * 16] =
                    acc0[i][j][q] + acc1[i][j][q] * (1.0f / 4096.0f);
}

// ---------------- LIF scan: H[t,b,n] -> spike bitmasks (exact reference arithmetic) ---------
__global__ __launch_bounds__(256) void lif_scan(const float* __restrict__ H,
                                                unsigned long long* __restrict__ mask) {
    const int g = blockIdx.x * 256 + threadIdx.x;
    const int b = g >> 10;
    const int n = g & 1023;
    const int word = n >> 6;
    const bool lane0 = (threadIdx.x & 63) == 0;

    float v = 0.0f;
    float buf[8];
#pragma unroll
    for (int j = 0; j < 8; ++j) buf[j] = H[(size_t)j * SROW + g];

    for (int t0 = 0; t0 < TT; t0 += 8) {
        float nbuf[8];
        if (t0 + 8 < TT) {
#pragma unroll
            for (int j = 0; j < 8; ++j) nbuf[j] = H[(size_t)(t0 + 8 + j) * SROW + g];
        } else {
#pragma unroll
            for (int j = 0; j < 8; ++j) nbuf[j] = 0.f;
        }
#pragma unroll
        for (int j = 0; j < 8; ++j) {
            const float x = buf[j];
            const float h = v + (x - v) * 0.5f;
            const bool s = (h >= 1.0f);
            v = s ? 0.0f : h;
            const unsigned long long m = __ballot(s);
            if (lane0) mask[((size_t)(t0 + j) * BB + b) * 16 + word] = m;
        }
#pragma unroll
        for (int j = 0; j < 8; ++j) buf[j] = nbuf[j];
    }
}

// ---------------- sparse GEMM2: out[r,:] = sum_{n: spike} W2T[n,:] ---------------------------
__global__ __launch_bounds__(256) void spike_matmul(const unsigned long long* __restrict__ mask,
                                                    const float* __restrict__ W2T,
                                                    float* __restrict__ out) {
    __shared__ unsigned long long sw[16];
    const int r = blockIdx.x;
    const int tid = threadIdx.x;
    if (tid < 16) sw[tid] = mask[(size_t)r * 16 + tid];
    __syncthreads();

    f4 acc = (f4)0.0f;
#pragma unroll 1
    for (int w = 0; w < 16; ++w) {
        unsigned long long bits = sw[w];
        while (bits) {
            const int n = w * 64 + (__ffsll(bits) - 1);
            bits &= bits - 1;
            const f4 rv = reinterpret_cast<const f4*>(W2T + (size_t)n * NN)[tid];
            acc[0] += rv[0]; acc[1] += rv[1]; acc[2] += rv[2]; acc[3] += rv[3];
        }
    }
    reinterpret_cast<f4*>(out + (size_t)r * NN)[tid] = acc;
}

// ---------------- W2 transpose (fallback path only) -----------------------------------------
__global__ __launch_bounds__(256) void transpose_nn(const float* __restrict__ in,
                                                    float* __restrict__ out) {
    __shared__ float tile[32][33];
    const int bx = blockIdx.x * 32, by = blockIdx.y * 32;
    const int tx = threadIdx.x, ty = threadIdx.y;
#pragma unroll
    for (int j = 0; j < 32; j += 8)
        tile[ty + j][tx] = in[(size_t)(by + ty + j) * NN + bx + tx];
    __syncthreads();
#pragma unroll
    for (int j = 0; j < 32; j += 8)
        out[(size_t)(bx + ty + j) * NN + by + tx] = tile[tx][ty + j];
}

// ---------------- fallback fp32 GEMM (used only if ws too small) -----------------------------
#define BM 128
#define BN 64
#define BK 16
__global__ __launch_bounds__(256, 4) void gemm1_f32(const float* __restrict__ A,
                                                    const float* __restrict__ B,
                                                    float* __restrict__ C) {
    __shared__ float Asb[2][BK][132];
    __shared__ float Bsb[2][BK][68];
    const int tid = threadIdx.x;
    const int ty = tid >> 4;
    const int tx = tid & 15;
    const int rowBase = blockIdx.y * BM;
    const int colBase = blockIdx.x * BN;
    const int sr = tid >> 2;
    const int sk = (tid & 3) * 4;

    const float* Ap0 = A + (size_t)(rowBase + sr) * NN + sk;
    const float* Ap1 = Ap0 + (size_t)64 * NN;
    const float* Bp  = B + (size_t)(colBase + sr) * NN + sk;

    v2f acc[4][4];
#pragma unroll
    for (int i = 0; i < 4; ++i)
#pragma unroll
        for (int j = 0; j < 4; ++j) acc[i][j] = (v2f){0.f, 0.f};

    float4 ra0 = *(const float4*)Ap0;
    float4 ra1 = *(const float4*)Ap1;
    float4 rb  = *(const float4*)Bp;

#define STW(buf)                                                                       \
    do {                                                                               \
        Asb[buf][sk + 0][sr] = ra0.x; Asb[buf][sk + 1][sr] = ra0.y;                    \
        Asb[buf][sk + 2][sr] = ra0.z; Asb[buf][sk + 3][sr] = ra0.w;                    \
        Asb[buf][sk + 0][sr + 64] = ra1.x; Asb[buf][sk + 1][sr + 64] = ra1.y;          \
        Asb[buf][sk + 2][sr + 64] = ra1.z; Asb[buf][sk + 3][sr + 64] = ra1.w;          \
        Bsb[buf][sk + 0][sr] = rb.x;  Bsb[buf][sk + 1][sr] = rb.y;                     \
        Bsb[buf][sk + 2][sr] = rb.z;  Bsb[buf][sk + 3][sr] = rb.w;                     \
    } while (0)

    STW(0);
    __syncthreads();
    const int NT = NN / BK;
    for (int t = 0; t < NT; ++t) {
        const int cur = t & 1;
        if (t < NT - 1) {
            const int ko = (t + 1) * BK;
            ra0 = *(const float4*)(Ap0 + ko);
            ra1 = *(const float4*)(Ap1 + ko);
            rb  = *(const float4*)(Bp + ko);
        }
#pragma unroll
        for (int k = 0; k < BK; ++k) {
            const v2f* ap = (const v2f*)&Asb[cur][k][ty * 8];
            const float4 bf = *(const float4*)&Bsb[cur][k][tx * 4];
            const float bb[4] = {bf.x, bf.y, bf.z, bf.w};
            const v2f a0 = ap[0], a1 = ap[1], a2 = ap[2], a3 = ap[3];
#pragma unroll
            for (int j = 0; j < 4; ++j) {
                const v2f bd = {bb[j], bb[j]};
                acc[0][j] = V2FMA(a0, bd, acc[0][j]);
                acc[1][j] = V2FMA(a1, bd, acc[1][j]);
                acc[2][j] = V2FMA(a2, bd, acc[2][j]);
                acc[3][j] = V2FMA(a3, bd, acc[3][j]);
            }
        }
        if (t < NT - 1) STW(cur ^ 1);
        __syncthreads();
    }
#undef STW
    float* Cp = C + (size_t)(rowBase + ty * 8) * NN + colBase + tx * 4;
#pragma unroll
    for (int rp = 0; rp < 4; ++rp) {
        float4 lo = {acc[rp][0][0], acc[rp][1][0], acc[rp][2][0], acc[rp][3][0]};
        float4 hi = {acc[rp][0][1], acc[rp][1][1], acc[rp][2][1], acc[rp][3][1]};
        *(float4*)(Cp + (size_t)(2 * rp) * NN)     = lo;
        *(float4*)(Cp + (size_t)(2 * rp + 1) * NN) = hi;
    }
}

extern "C" void kernel_launch(void* const* d_in, const int* in_sizes, int n_in,
                              void* d_out, int out_size, void* d_ws, size_t ws_size,
                              hipStream_t stream) {
    const float* x  = (const float*)d_in[0];
    const float* W1 = (const float*)d_in[1];
    const float* W2 = (const float*)d_in[2];
    float* out = (float*)d_out;

    unsigned long long* mask = (unsigned long long*)d_ws;
    float* W2T = (float*)((char*)d_ws + 1 * MiB);

    if (ws_size >= 43 * MiB) {
        _Float16* A0 = (_Float16*)((char*)d_ws + 5 * MiB);
        _Float16* A1 = (_Float16*)((char*)d_ws + 22 * MiB);
        _Float16* B0 = (_Float16*)((char*)d_ws + 39 * MiB);
        _Float16* B1 = (_Float16*)((char*)d_ws + 41 * MiB);

        prep<<<8192 + 1024 + 1024, 256, 0, stream>>>(x, W1, W2, A0, A1, B0, B1, W2T);
        gemm_split<<<dim3(NN / 128, MROWS / 128), 256, 0, stream>>>(A0, A1, B0, B1, out);
    } else {
        transpose_nn<<<dim3(32, 32), dim3(32, 8), 0, stream>>>(W2, W2T);
        gemm1_f32<<<dim3(NN / BN, MROWS / BM), 256, 0, stream>>>(x, W1, out);
    }
    lif_scan<<<SROW / 256, 256, 0, stream>>>(out, mask);
    spike_matmul<<<MROWS, 256, 0, stream>>>(mask, W2T, out);
}

// Round 6
// 179.410 us; speedup vs baseline: 1.8908x; 1.0103x over previous
//
#include <hip/hip_runtime.h>
#include <hip/hip_bf16.h>
#include <stdint.h>

// Problem: x[128,64,1024] fp32; W1,W2 [1024,1024] fp32 (torch Linear, y = x @ W^T)
//   h = x @ W1^T ; spikes = LIF_scan(h) ; out = spikes @ W2^T  (spike rate ~0.1-0.2%)
//
// GEMM1 via f16 2-split on MFMA: a = a0 + a1/4096 (+ r ~ 2^-22|a|),
//   A.B^T ~= A0B0 + (A0B1s + A1sB0)/4096
// Round 6: (1) A-split moved IN-KERNEL (stage raw fp32 x — same bytes as A0+A1; split to
// f16 pairs in registers after ds_read) -> prep shrinks 10240->2048 blocks, -67MB HBM.
// (2) XCD-aware block remap: col-tiles sharing an A row-panel -> same XCD L2.
// (3) lif_scan prefetch depth 16.
// ws: [0,1M) masks | [1,5M) W2T | [5M) B0 2M | [7M) B1 2M  (needs 9 MiB; else fp32 fallback)

#define TT 128
#define BB 64
#define NN 1024
#define MROWS (TT * BB)          // 8192
#define SROW  (BB * NN)          // 65536
#define MiB   ((size_t)1048576)

typedef _Float16 h8  __attribute__((ext_vector_type(8)));
typedef _Float16 h4v __attribute__((ext_vector_type(4)));
typedef float    f4  __attribute__((ext_vector_type(4)));
typedef float    v2f __attribute__((ext_vector_type(2)));

#if __has_builtin(__builtin_elementwise_fma)
#define V2FMA(a, b, c) __builtin_elementwise_fma((a), (b), (c))
#else
static __device__ __forceinline__ v2f v2fma_(v2f a, v2f b, v2f c) {
    v2f r; r[0] = fmaf(a[0], b[0], c[0]); r[1] = fmaf(a[1], b[1], c[1]); return r;
}
#define V2FMA(a, b, c) v2fma_((a), (b), (c))
#endif

#define GL2LDS(g, l) __builtin_amdgcn_global_load_lds(                         \
    (const __attribute__((address_space(1))) void*)(const void*)(g),           \
    (__attribute__((address_space(3))) void*)(void*)(l), 16, 0, 0)

// ---------------- prep: split W1, transpose W2 (x-split now lives in the GEMM) --------------
__global__ __launch_bounds__(256) void prep(const float* __restrict__ W1,
                                            const float* __restrict__ W2,
                                            _Float16* __restrict__ B0, _Float16* __restrict__ B1,
                                            float* __restrict__ W2T) {
    const int nb = blockIdx.x;
    const int tid = threadIdx.x;
    if (nb < 1024) {
        const int i = nb * 256 + tid;
        const float4 v = reinterpret_cast<const float4*>(W1)[i];
        const float f[4] = {v.x, v.y, v.z, v.w};
        h4v a0, a1;
#pragma unroll
        for (int j = 0; j < 4; ++j) {
            const _Float16 c = (_Float16)f[j];
            a0[j] = c;
            a1[j] = (_Float16)((f[j] - (float)c) * 4096.0f);  // scaled: no f16 subnormals
        }
        reinterpret_cast<h4v*>(B0)[i] = a0;
        reinterpret_cast<h4v*>(B1)[i] = a1;
    } else {
        __shared__ float tile[32][33];
        const int tIdx = nb - 1024;
        const int bx = (tIdx & 31) * 32, by = (tIdx >> 5) * 32;
        const int tx = tid & 31, ty = tid >> 5;          // 32 x 8
#pragma unroll
        for (int j = 0; j < 32; j += 8)
            tile[ty + j][tx] = W2[(size_t)(by + ty + j) * NN + bx + tx];
        __syncthreads();
#pragma unroll
        for (int j = 0; j < 32; j += 8)
            W2T[(size_t)(bx + ty + j) * NN + by + tx] = tile[tx][ty + j];
    }
}

// ---------------- MFMA GEMM: C[8192,1024] f32, merged 3-product K-loop, in-kernel A-split ----
// 128x128 tile, 4 waves (2x2), 16x16x32 f16 MFMA.
// A tile staged as raw fp32: [row 0..127][k 0..31] f32, row = 128B = 8 chunks of 16B,
//   phys chunk = logical ^ (row&7)   (both-sides swizzle, rule #21).
// B tiles f16: [row][k] 64B rows, 4 chunks, phys = logical ^ ((row>>1)&3)  (r5-verified, 0 conf).
// XCD remap: linear i -> A-panel p=(i>>6)*8+(i&7), col c=(i>>3)&7, so a panel's 8 col-tiles
// share one XCD's L2 (dispatch round-robins i%8 across XCDs).
__global__ __launch_bounds__(256, 2) void gemm_split(const float* __restrict__ X,
                                                     const _Float16* __restrict__ B0g,
                                                     const _Float16* __restrict__ B1g,
                                                     float* __restrict__ C) {
    __shared__ float    As[2][4096];                   // 32 KB
    __shared__ _Float16 Bs0[2][4096], Bs1[2][4096];    // 16 + 16 KB
    const int tid  = threadIdx.x;
    const int lane = tid & 63;
    const int wid  = tid >> 6;
    const int wr   = wid >> 1, wc = wid & 1;

    const int ib = blockIdx.x;
    const int p  = ((ib >> 6) << 3) + (ib & 7);        // A row-panel 0..63
    const int cc = (ib >> 3) & 7;                      // col tile 0..7
    const int rowBase = p * 128;
    const int colBase = cc * 128;

    // --- A staging: wave w covers rows [w*32, w*32+32) as 4 insts of 8 rows (1KB each).
    // lane l -> row +(l>>3), phys slot l&7, global chunk (l&7)^(l>>3)  (row&7 == l>>3).
    const size_t aOff = (size_t)(rowBase + wid * 32 + (lane >> 3)) * NN
                      + (((lane & 7) ^ (lane >> 3)) << 2);
    const int ldsA = wid * 1024;                       // f32 elems; inst j at +j*256

    // --- B staging: wave w covers rows [w*32,+32) as 2 insts of 16 rows.
    const int srowB = wid * 32 + (lane >> 2);
    const size_t bOff = (size_t)(colBase + srowB) * NN
                      + (((lane & 3) ^ ((srowB >> 1) & 3)) << 3);
    const int ldsB = wid * 1024;                       // f16 elems; inst at +0 / +512

    // --- fragment read addrs (precomputed, lane-constant)
    int fA0[4], fA1[4], fB[4];
#pragma unroll
    for (int i = 0; i < 4; ++i) {
        const int ra = wr * 64 + i * 16 + (lane & 15);
        const int rb = wc * 64 + i * 16 + (lane & 15);
        const int ca = (lane >> 4) * 2;                // logical 16B chunk pair in fp32 row
        fA0[i] = ra * 32 + (((ca + 0) ^ (ra & 7)) << 2);
        fA1[i] = ra * 32 + (((ca + 1) ^ (ra & 7)) << 2);
        fB[i]  = rb * 32 + (((lane >> 4) ^ ((rb >> 1) & 3)) << 3);
    }

    f4 acc0[4][4], acc1[4][4];
#pragma unroll
    for (int i = 0; i < 4; ++i)
#pragma unroll
        for (int j = 0; j < 4; ++j) { acc0[i][j] = (f4)0.0f; acc1[i][j] = (f4)0.0f; }

#define STAGE(bi, K0)                                              \
    do {                                                           \
        GL2LDS(X + aOff + (size_t)0  * NN + (K0), &As[bi][ldsA]);          \
        GL2LDS(X + aOff + (size_t)8  * NN + (K0), &As[bi][ldsA + 256]);    \
        GL2LDS(X + aOff + (size_t)16 * NN + (K0), &As[bi][ldsA + 512]);    \
        GL2LDS(X + aOff + (size_t)24 * NN + (K0), &As[bi][ldsA + 768]);    \
        GL2LDS(B0g + bOff + (K0),                  &Bs0[bi][ldsB]);        \
        GL2LDS(B0g + bOff + (size_t)16 * NN + (K0), &Bs0[bi][ldsB + 512]); \
        GL2LDS(B1g + bOff + (K0),                  &Bs1[bi][ldsB]);        \
        GL2LDS(B1g + bOff + (size_t)16 * NN + (K0), &Bs1[bi][ldsB + 512]); \
    } while (0)

    STAGE(0, 0);
    __syncthreads();

    const int NT = NN / 32;                  // 32 phases
    for (int t = 0; t < NT; ++t) {
        const int cur = t & 1;
        if (t < NT - 1) STAGE(cur ^ 1, (t + 1) * 32);   // issue next-tile loads before compute

        h8 a0f[4], a1f[4], b0f[4], b1f[4];
#pragma unroll
        for (int i = 0; i < 4; ++i) {
            const f4 lo = *(const f4*)&As[cur][fA0[i]];   // k 8j..8j+3
            const f4 hi = *(const f4*)&As[cur][fA1[i]];   // k 8j+4..8j+7
#pragma unroll
            for (int e = 0; e < 4; ++e) {
                const float fl = lo[e], fh = hi[e];
                const _Float16 cl = (_Float16)fl, ch = (_Float16)fh;
                a0f[i][e]     = cl;
                a0f[i][4 + e] = ch;
                a1f[i][e]     = (_Float16)((fl - (float)cl) * 4096.0f);
                a1f[i][4 + e] = (_Float16)((fh - (float)ch) * 4096.0f);
            }
            b0f[i] = *(const h8*)&Bs0[cur][fB[i]];
            b1f[i] = *(const h8*)&Bs1[cur][fB[i]];
        }
#pragma unroll
        for (int i = 0; i < 4; ++i)
#pragma unroll
            for (int j = 0; j < 4; ++j) {
                acc0[i][j] = __builtin_amdgcn_mfma_f32_16x16x32_f16(a0f[i], b0f[j], acc0[i][j], 0, 0, 0);
                acc1[i][j] = __builtin_amdgcn_mfma_f32_16x16x32_f16(a0f[i], b1f[j], acc1[i][j], 0, 0, 0);
                acc1[i][j] = __builtin_amdgcn_mfma_f32_16x16x32_f16(a1f[i], b0f[j], acc1[i][j], 0, 0, 0);
            }
        __syncthreads();    // drains stage vmcnt + protects buffer reuse
    }
#undef STAGE

    // C/D layout (m89-verified): col = lane&15, row = (lane>>4)*4 + reg
    const int orow = rowBase + wr * 64 + (lane >> 4) * 4;
    const int ocol = colBase + wc * 64 + (lane & 15);
#pragma unroll
    for (int i = 0; i < 4; ++i)
#pragma unroll
        for (int j = 0; j < 4; ++j)
#pragma unroll
            for (int q = 0; q < 4; ++q)
                C[(size_t)(orow + i * 16 + q) * NN + ocol + j * 16] =
                    acc0[i][j][q] + acc1[i][j][q] * (1.0f / 4096.0f);
}

// ---------------- LIF scan: H[t,b,n] -> spike bitmasks (exact reference arithmetic) ---------
// depth-16 prefetch: 65536 threads x 16 x 4B = 4MB in flight (Little's law target ~5.7MB).
__global__ __launch_bounds__(256) void lif_scan(const float* __restrict__ H,
                                                unsigned long long* __restrict__ mask) {
    const int g = blockIdx.x * 256 + threadIdx.x;
    const int b = g >> 10;
    const int n = g & 1023;
    const int word = n >> 6;
    const bool lane0 = (threadIdx.x & 63) == 0;

    float v = 0.0f;
    float buf[16];
#pragma unroll
    for (int j = 0; j < 16; ++j) buf[j] = H[(size_t)j * SROW + g];

    for (int t0 = 0; t0 < TT; t0 += 16) {
        float nbuf[16];
        if (t0 + 16 < TT) {
#pragma unroll
            for (int j = 0; j < 16; ++j) nbuf[j] = H[(size_t)(t0 + 16 + j) * SROW + g];
        } else {
#pragma unroll
            for (int j = 0; j < 16; ++j) nbuf[j] = 0.f;
        }
#pragma unroll
        for (int j = 0; j < 16; ++j) {
            const float x = buf[j];
            const float h = v + (x - v) * 0.5f;
            const bool s = (h >= 1.0f);
            v = s ? 0.0f : h;
            const unsigned long long m = __ballot(s);
            if (lane0) mask[((size_t)(t0 + j) * BB + b) * 16 + word] = m;
        }
#pragma unroll
        for (int j = 0; j < 16; ++j) buf[j] = nbuf[j];
    }
}

// ---------------- sparse GEMM2: out[r,:] = sum_{n: spike} W2T[n,:] ---------------------------
__global__ __launch_bounds__(256) void spike_matmul(const unsigned long long* __restrict__ mask,
                                                    const float* __restrict__ W2T,
                                                    float* __restrict__ out) {
    __shared__ unsigned long long sw[16];
    const int r = blockIdx.x;
    const int tid = threadIdx.x;
    if (tid < 16) sw[tid] = mask[(size_t)r * 16 + tid];
    __syncthreads();

    f4 acc = (f4)0.0f;
#pragma unroll 1
    for (int w = 0; w < 16; ++w) {
        unsigned long long bits = sw[w];
        while (bits) {
            const int n = w * 64 + (__ffsll(bits) - 1);
            bits &= bits - 1;
            const f4 rv = reinterpret_cast<const f4*>(W2T + (size_t)n * NN)[tid];
            acc[0] += rv[0]; acc[1] += rv[1]; acc[2] += rv[2]; acc[3] += rv[3];
        }
    }
    reinterpret_cast<f4*>(out + (size_t)r * NN)[tid] = acc;
}

// ---------------- W2 transpose (fallback path only) -----------------------------------------
__global__ __launch_bounds__(256) void transpose_nn(const float* __restrict__ in,
                                                    float* __restrict__ out) {
    __shared__ float tile[32][33];
    const int bx = blockIdx.x * 32, by = blockIdx.y * 32;
    const int tx = threadIdx.x, ty = threadIdx.y;
#pragma unroll
    for (int j = 0; j < 32; j += 8)
        tile[ty + j][tx] = in[(size_t)(by + ty + j) * NN + bx + tx];
    __syncthreads();
#pragma unroll
    for (int j = 0; j < 32; j += 8)
        out[(size_t)(bx + ty + j) * NN + by + tx] = tile[tx][ty + j];
}

// ---------------- fallback fp32 GEMM (used only if ws too small) -----------------------------
#define BM 128
#define BN 64
#define BK 16
__global__ __launch_bounds__(256, 4) void gemm1_f32(const float* __restrict__ A,
                                                    const float* __restrict__ B,
                                                    float* __restrict__ C) {
    __shared__ float Asb[2][BK][132];
    __shared__ float Bsb[2][BK][68];
    const int tid = threadIdx.x;
    const int ty = tid >> 4;
    const int tx = tid & 15;
    const int rowBase = blockIdx.y * BM;
    const int colBase = blockIdx.x * BN;
    const int sr = tid >> 2;
    const int sk = (tid & 3) * 4;

    const float* Ap0 = A + (size_t)(rowBase + sr) * NN + sk;
    const float* Ap1 = Ap0 + (size_t)64 * NN;
    const float* Bp  = B + (size_t)(colBase + sr) * NN + sk;

    v2f acc[4][4];
#pragma unroll
    for (int i = 0; i < 4; ++i)
#pragma unroll
        for (int j = 0; j < 4; ++j) acc[i][j] = (v2f){0.f, 0.f};

    float4 ra0 = *(const float4*)Ap0;
    float4 ra1 = *(const float4*)Ap1;
    float4 rb  = *(const float4*)Bp;

#define STW(buf)                                                                       \
    do {                                                                               \
        Asb[buf][sk + 0][sr] = ra0.x; Asb[buf][sk + 1][sr] = ra0.y;                    \
        Asb[buf][sk + 2][sr] = ra0.z; Asb[buf][sk + 3][sr] = ra0.w;                    \
        Asb[buf][sk + 0][sr + 64] = ra1.x; Asb[buf][sk + 1][sr + 64] = ra1.y;          \
        Asb[buf][sk + 2][sr + 64] = ra1.z; Asb[buf][sk + 3][sr + 64] = ra1.w;          \
        Bsb[buf][sk + 0][sr] = rb.x;  Bsb[buf][sk + 1][sr] = rb.y;                     \
        Bsb[buf][sk + 2][sr] = rb.z;  Bsb[buf][sk + 3][sr] = rb.w;                     \
    } while (0)

    STW(0);
    __syncthreads();
    const int NT = NN / BK;
    for (int t = 0; t < NT; ++t) {
        const int cur = t & 1;
        if (t < NT - 1) {
            const int ko = (t + 1) * BK;
            ra0 = *(const float4*)(Ap0 + ko);
            ra1 = *(const float4*)(Ap1 + ko);
            rb  = *(const float4*)(Bp + ko);
        }
#pragma unroll
        for (int k = 0; k < BK; ++k) {
            const v2f* ap = (const v2f*)&Asb[cur][k][ty * 8];
            const float4 bf = *(const float4*)&Bsb[cur][k][tx * 4];
            const float bb[4] = {bf.x, bf.y, bf.z, bf.w};
            const v2f a0 = ap[0], a1 = ap[1], a2 = ap[2], a3 = ap[3];
#pragma unroll
            for (int j = 0; j < 4; ++j) {
                const v2f bd = {bb[j], bb[j]};
                acc[0][j] = V2FMA(a0, bd, acc[0][j]);
                acc[1][j] = V2FMA(a1, bd, acc[1][j]);
                acc[2][j] = V2FMA(a2, bd, acc[2][j]);
                acc[3][j] = V2FMA(a3, bd, acc[3][j]);
            }
        }
        if (t < NT - 1) STW(cur ^ 1);
        __syncthreads();
    }
#undef STW
    float* Cp = C + (size_t)(rowBase + ty * 8) * NN + colBase + tx * 4;
#pragma unroll
    for (int rp = 0; rp < 4; ++rp) {
        float4 lo = {acc[rp][0][0], acc[rp][1][0], acc[rp][2][0], acc[rp][3][0]};
        float4 hi = {acc[rp][0][1], acc[rp][1][1], acc[rp][2][1], acc[rp][3][1]};
        *(float4*)(Cp + (size_t)(2 * rp) * NN)     = lo;
        *(float4*)(Cp + (size_t)(2 * rp + 1) * NN) = hi;
    }
}

extern "C" void kernel_launch(void* const* d_in, const int* in_sizes, int n_in,
                              void* d_out, int out_size, void* d_ws, size_t ws_size,
                              hipStream_t stream) {
    const float* x  = (const float*)d_in[0];
    const float* W1 = (const float*)d_in[1];
    const float* W2 = (const float*)d_in[2];
    float* out = (float*)d_out;

    unsigned long long* mask = (unsigned long long*)d_ws;
    float* W2T = (float*)((char*)d_ws + 1 * MiB);

    if (ws_size >= 9 * MiB) {
        _Float16* B0 = (_Float16*)((char*)d_ws + 5 * MiB);
        _Float16* B1 = (_Float16*)((char*)d_ws + 7 * MiB);

        prep<<<2048, 256, 0, stream>>>(W1, W2, B0, B1, W2T);
        gemm_split<<<512, 256, 0, stream>>>(x, B0, B1, out);
    } else {
        transpose_nn<<<dim3(32, 32), dim3(32, 8), 0, stream>>>(W2, W2T);
        gemm1_f32<<<dim3(NN / BN, MROWS / BM), 256, 0, stream>>>(x, W1, out);
    }
    lif_scan<<<SROW / 256, 256, 0, stream>>>(out, mask);
    spike_matmul<<<MROWS, 256, 0, stream>>>(mask, W2T, out);
}